// Round 3
// baseline (4806.142 us; speedup 1.0000x reference)
//
#include <hip/hip_runtime.h>

typedef unsigned int u32;

#define BT 6272      // B*T = 32*196
#define TT 196
#define DM 512
#define FFD 2048
#define NE 8
#define FC 256       // MoE hidden chunk

// ---------------- patchify: x[B,1,224,224] f32 -> patches[BT,256] f32 ----------------
__global__ void patchify_k(const float* __restrict__ x, float* __restrict__ out){
  int bt = blockIdx.x;             // 0..6271
  int t = bt % TT, b = bt / TT;
  int pd = threadIdx.x;            // 0..255
  int g1 = t / 14, g2 = t % 14, p1 = pd >> 4, p2 = pd & 15;
  int src = (b*224 + g1*16 + p1)*224 + g2*16 + p2;
  out[(size_t)bt*256 + pd] = x[src];
}

// ---------------- posenc[196,512] f32 (double-precision trig) ----------------
__global__ void posenc_k(float* __restrict__ pe){
  int t = blockIdx.x, c = threadIdx.x;   // grid 196, block 512
  int m2 = c & ~1;
  double ang = (double)t * pow(10000.0, -(double)m2 / 512.0);
  double vv = (c & 1) ? cos(ang) : sin(ang);
  pe[t*DM + c] = (float)vv;
}

// ---------------- generic fp32 GEMM: C[M,N] = A[M,K] @ Bw[K,N] (+bias)(+pe)(+f32 mirror) ----------------
__global__ __launch_bounds__(256)
void gemm_f32(const float* __restrict__ A, const float* __restrict__ Bw,
              float* __restrict__ C, const float* __restrict__ bias,
              const float* __restrict__ pe, float* __restrict__ obf,
              int M, int N, int K)
{
  __shared__ float As[16][68];
  __shared__ float Bs[16][68];
  int tid = threadIdx.x;
  int row0 = blockIdx.y << 6, col0 = blockIdx.x << 6;
  int ar = tid >> 2, ak = (tid & 3) << 2;     // A staging: 64 rows x 16 k
  int bk = tid >> 4, bn = (tid & 15) << 2;    // B staging: 16 k x 64 n
  int n0 = (tid & 15) << 2, m0 = (tid >> 4) << 2;
  float acc[4][4] = {};
  bool arow_ok = (row0 + ar) < M;
  const float* Aldg = A + (size_t)(row0 + ar) * K + ak;
  const float* Bldg = Bw + (size_t)bk * N + col0 + bn;
  for (int k0 = 0; k0 < K; k0 += 16){
    float4 av = make_float4(0.f,0.f,0.f,0.f);
    if (arow_ok) av = *(const float4*)(Aldg + k0);
    float4 bv = *(const float4*)(Bldg + (size_t)k0 * N);
    __syncthreads();
    As[ak+0][ar]=av.x; As[ak+1][ar]=av.y; As[ak+2][ar]=av.z; As[ak+3][ar]=av.w;
    *(float4*)&Bs[bk][bn] = bv;
    __syncthreads();
    #pragma unroll
    for (int kk = 0; kk < 16; ++kk){
      float4 a = *(const float4*)&As[kk][m0];
      float4 b = *(const float4*)&Bs[kk][n0];
      float aa[4] = {a.x,a.y,a.z,a.w};
      float bb[4] = {b.x,b.y,b.z,b.w};
      #pragma unroll
      for (int i = 0; i < 4; ++i)
        #pragma unroll
        for (int j = 0; j < 4; ++j)
          acc[i][j] += aa[i]*bb[j];
    }
  }
  float4 badd = make_float4(0.f,0.f,0.f,0.f);
  if (bias) badd = *(const float4*)(bias + col0 + n0);
  #pragma unroll
  for (int i = 0; i < 4; ++i){
    int gr = row0 + m0 + i;
    if (gr < M){
      float4 r = make_float4(acc[i][0]+badd.x, acc[i][1]+badd.y, acc[i][2]+badd.z, acc[i][3]+badd.w);
      if (pe){
        float4 pv = *(const float4*)(pe + (size_t)(gr % TT)*DM + col0 + n0);
        r.x += pv.x; r.y += pv.y; r.z += pv.z; r.w += pv.w;
      }
      *(float4*)(C + (size_t)gr*N + col0 + n0) = r;
      if (obf) *(float4*)(obf + (size_t)gr*N + col0 + n0) = r;
    }
  }
}

// ---------------- fused causal attention, one block per (b,h), T=196 hs=64 ----------------
// NOTE: o may alias q (block reads its q row strictly before writing the same o row,
// and touches only its own (b,h) column slice) -> no __restrict__ on q/o.
__global__ __launch_bounds__(256)
void attn_k(const float* q, const float* __restrict__ k,
            const float* __restrict__ v, float* o)
{
  __shared__ float Ks[TT][68];
  __shared__ float qr[4][64];
  __shared__ float sc[4][200];
  int bh = blockIdx.x; int b = bh >> 3, h = bh & 7;
  size_t base = (size_t)b * TT * DM + h * 64;
  const float* qb = q + base;
  const float* kb = k + base;
  const float* vb = v + base;
  float*       ob = o + base;
  int tid = threadIdx.x;
  for (int idx = tid; idx < TT*64; idx += 256){
    int t = idx >> 6, d = idx & 63;
    Ks[t][d] = kb[(size_t)t*DM + d];
  }
  __syncthreads();
  int w = tid >> 6, lane = tid & 63;
  for (int i = w; i < TT; i += 4){            // 49 iterations for every wave (uniform)
    qr[w][lane] = qb[(size_t)i*DM + lane];
    __syncthreads();
    float s[4]; float mx = -3e38f;
    #pragma unroll
    for (int u = 0; u < 4; ++u){
      int j = (u<<6) + lane;
      float a = -3e38f;
      if (j <= i){
        float accd = 0.f;
        #pragma unroll
        for (int d = 0; d < 64; d += 4){
          float4 kv = *(const float4*)&Ks[j][d];
          accd += qr[w][d]*kv.x + qr[w][d+1]*kv.y + qr[w][d+2]*kv.z + qr[w][d+3]*kv.w;
        }
        a = accd * 0.125f;
      }
      s[u] = a; mx = fmaxf(mx, a);
    }
    #pragma unroll
    for (int off = 32; off; off >>= 1) mx = fmaxf(mx, __shfl_xor(mx, off, 64));
    float sum = 0.f;
    #pragma unroll
    for (int u = 0; u < 4; ++u){
      int j = (u<<6) + lane;
      float e = (j <= i) ? expf(s[u] - mx) : 0.f;
      s[u] = e; sum += e;
    }
    #pragma unroll
    for (int off = 32; off; off >>= 1) sum += __shfl_xor(sum, off, 64);
    float inv = 1.f / sum;
    #pragma unroll
    for (int u = 0; u < 4; ++u){
      int j = (u<<6) + lane;
      if (j < TT) sc[w][j] = s[u] * inv;
    }
    __syncthreads();
    float acc2 = 0.f;
    int j = 0;
    for (; j + 3 <= i; j += 4){
      acc2 += sc[w][j]  *vb[(size_t)j*DM + lane]
            + sc[w][j+1]*vb[(size_t)(j+1)*DM + lane]
            + sc[w][j+2]*vb[(size_t)(j+2)*DM + lane]
            + sc[w][j+3]*vb[(size_t)(j+3)*DM + lane];
    }
    for (; j <= i; ++j) acc2 += sc[w][j]*vb[(size_t)j*DM + lane];
    ob[(size_t)i*DM + lane] = acc2;
    __syncthreads();
  }
}

// ---------------- router: noisy top-2, per-token gates, expert counts ----------------
__global__ __launch_bounds__(256)
void router_k(const float* __restrict__ X, const float* __restrict__ rtW, const float* __restrict__ rtb,
              const float* __restrict__ rnW, const float* __restrict__ rnb, const float* __restrict__ nz,
              int* __restrict__ tok_e, float* __restrict__ tok_g, int* __restrict__ counts)
{
  int w = threadIdx.x >> 6, lane = threadIdx.x & 63;
  int t = (blockIdx.x << 2) + w;
  const float* xr = X + (size_t)t * DM;
  float at[8] = {}, an[8] = {};
  #pragma unroll
  for (int u = 0; u < 8; ++u){
    int d = (u<<6) + lane;
    float xv = xr[d];
    float4 wt0 = *(const float4*)(rtW + (size_t)d*8);
    float4 wt1 = *(const float4*)(rtW + (size_t)d*8 + 4);
    float4 wn0 = *(const float4*)(rnW + (size_t)d*8);
    float4 wn1 = *(const float4*)(rnW + (size_t)d*8 + 4);
    at[0]+=xv*wt0.x; at[1]+=xv*wt0.y; at[2]+=xv*wt0.z; at[3]+=xv*wt0.w;
    at[4]+=xv*wt1.x; at[5]+=xv*wt1.y; at[6]+=xv*wt1.z; at[7]+=xv*wt1.w;
    an[0]+=xv*wn0.x; an[1]+=xv*wn0.y; an[2]+=xv*wn0.z; an[3]+=xv*wn0.w;
    an[4]+=xv*wn1.x; an[5]+=xv*wn1.y; an[6]+=xv*wn1.z; an[7]+=xv*wn1.w;
  }
  #pragma unroll
  for (int off = 32; off; off >>= 1){
    #pragma unroll
    for (int e = 0; e < 8; ++e){
      at[e] += __shfl_xor(at[e], off, 64);
      an[e] += __shfl_xor(an[e], off, 64);
    }
  }
  if (lane == 0){
    float ns[8];
    #pragma unroll
    for (int e = 0; e < 8; ++e){
      float lt = at[e] + rtb[e];
      float ln_ = an[e] + rnb[e];
      float sp = (ln_ > 0.f) ? (ln_ + log1pf(expf(-ln_))) : log1pf(expf(ln_));
      ns[e] = lt + nz[(size_t)t*8 + e] * sp;
    }
    int i1 = 0; float n1 = ns[0];
    #pragma unroll
    for (int e = 1; e < 8; ++e) if (ns[e] > n1){ n1 = ns[e]; i1 = e; }
    int i2 = -1; float n2 = -3e38f;
    #pragma unroll
    for (int e = 0; e < 8; ++e) if (e != i1 && ns[e] > n2){ n2 = ns[e]; i2 = e; }
    float ex = expf(n2 - n1);
    float inv = 1.f / (1.f + ex);
    tok_e[t*2]   = i1; tok_g[t*2]   = inv;
    tok_e[t*2+1] = i2; tok_g[t*2+1] = ex * inv;
    atomicAdd(counts + i1, 1);
    atomicAdd(counts + i2, 1);
  }
}

__global__ void scan_k(const int* __restrict__ counts, int* __restrict__ offs, int* __restrict__ cursors){
  if (threadIdx.x == 0){
    int s = 0;
    for (int e = 0; e < NE; ++e){ offs[e] = s; cursors[e] = s; s += counts[e]; }
    offs[NE] = s;
  }
}

__global__ void assign_k(const int* __restrict__ tok_e, const float* __restrict__ tok_g,
                         int* __restrict__ cursors, int* __restrict__ idx_c, float* __restrict__ gate_c){
  int t = blockIdx.x*256 + threadIdx.x;
  if (t >= BT) return;
  #pragma unroll
  for (int kk = 0; kk < 2; ++kk){
    int e = tok_e[t*2+kk];
    int p = atomicAdd(cursors + e, 1);
    idx_c[p] = t; gate_c[p] = tok_g[t*2+kk];
  }
}

// ---------------- expert GEMM1 (chunked): H1c[r, 0..FC) = relu(X[idx[r]] @ Wi_e[:, c0..c0+FC) + bi_e) ----------------
__global__ __launch_bounds__(256)
void gemm_moe1(const float* __restrict__ X, const float* __restrict__ Wi,
               const float* __restrict__ bi, const int* __restrict__ offs,
               const int* __restrict__ idx_c, float* __restrict__ H1, int c0)
{
  int e = blockIdx.z;
  int base = offs[e], cnt = offs[e+1] - base;
  int row0 = blockIdx.y << 6;
  if (row0 >= cnt) return;
  int col0 = blockIdx.x << 6;                 // within chunk [0, FC)
  __shared__ float As[16][68];
  __shared__ float Bs[16][68];
  __shared__ int ridx[64];
  int tid = threadIdx.x;
  if (tid < 64) ridx[tid] = (row0 + tid < cnt) ? idx_c[base + row0 + tid] : -1;
  __syncthreads();
  int ar = tid >> 2, ak = (tid & 3) << 2;
  int bk = tid >> 4, bn = (tid & 15) << 2;
  int n0 = (tid & 15) << 2, m0 = (tid >> 4) << 2;
  float acc[4][4] = {};
  const float* Bw = Wi + (size_t)e * DM * FFD + c0;
  int rr = ridx[ar];
  for (int k0 = 0; k0 < DM; k0 += 16){
    float4 av = make_float4(0.f,0.f,0.f,0.f);
    if (rr >= 0) av = *(const float4*)(X + (size_t)rr*DM + k0 + ak);
    float4 bv = *(const float4*)(Bw + (size_t)(k0+bk)*FFD + col0 + bn);
    __syncthreads();
    As[ak+0][ar]=av.x; As[ak+1][ar]=av.y; As[ak+2][ar]=av.z; As[ak+3][ar]=av.w;
    *(float4*)&Bs[bk][bn] = bv;
    __syncthreads();
    #pragma unroll
    for (int kk = 0; kk < 16; ++kk){
      float4 a = *(const float4*)&As[kk][m0];
      float4 b = *(const float4*)&Bs[kk][n0];
      float aa[4] = {a.x,a.y,a.z,a.w};
      float bb[4] = {b.x,b.y,b.z,b.w};
      #pragma unroll
      for (int i = 0; i < 4; ++i)
        #pragma unroll
        for (int j = 0; j < 4; ++j)
          acc[i][j] += aa[i]*bb[j];
    }
  }
  float4 badd = *(const float4*)(bi + (size_t)e*FFD + c0 + col0 + n0);
  #pragma unroll
  for (int i = 0; i < 4; ++i){
    int r = row0 + m0 + i;
    if (r < cnt){
      float4 rv = make_float4(fmaxf(acc[i][0]+badd.x,0.f), fmaxf(acc[i][1]+badd.y,0.f),
                              fmaxf(acc[i][2]+badd.z,0.f), fmaxf(acc[i][3]+badd.w,0.f));
      *(float4*)(H1 + (size_t)(base + r)*FC + col0 + n0) = rv;
    }
  }
}

// ---------------- expert GEMM2 (chunked): Y[tok] += gate * (H1c @ Wo_e[c0..c0+FC, :] (+ bo_e if c0==0)) ----------------
__global__ __launch_bounds__(256)
void gemm_moe2(const float* __restrict__ H1, const float* __restrict__ Wo,
               const float* __restrict__ bo, const int* __restrict__ offs,
               const int* __restrict__ idx_c, const float* __restrict__ gate_c,
               float* __restrict__ Y, int c0)
{
  int e = blockIdx.z;
  int base = offs[e], cnt = offs[e+1] - base;
  int row0 = blockIdx.y << 6;
  if (row0 >= cnt) return;
  int col0 = blockIdx.x << 6;
  __shared__ float As[16][68];
  __shared__ float Bs[16][68];
  __shared__ int ridx[64];
  __shared__ float rg[64];
  int tid = threadIdx.x;
  if (tid < 64){
    bool ok = (row0 + tid) < cnt;
    ridx[tid] = ok ? idx_c[base + row0 + tid] : -1;
    rg[tid]   = ok ? gate_c[base + row0 + tid] : 0.f;
  }
  __syncthreads();
  int ar = tid >> 2, ak = (tid & 3) << 2;
  int bk = tid >> 4, bn = (tid & 15) << 2;
  int n0 = (tid & 15) << 2, m0 = (tid >> 4) << 2;
  float acc[4][4] = {};
  const float* Bw = Wo + (size_t)e * FFD * DM + (size_t)c0 * DM;
  bool arow_ok = (row0 + ar) < cnt;
  const float* Aldg = H1 + (size_t)(base + row0 + ar)*FC + ak;
  for (int k0 = 0; k0 < FC; k0 += 16){
    float4 av = make_float4(0.f,0.f,0.f,0.f);
    if (arow_ok) av = *(const float4*)(Aldg + k0);
    float4 bv = *(const float4*)(Bw + (size_t)(k0+bk)*DM + col0 + bn);
    __syncthreads();
    As[ak+0][ar]=av.x; As[ak+1][ar]=av.y; As[ak+2][ar]=av.z; As[ak+3][ar]=av.w;
    *(float4*)&Bs[bk][bn] = bv;
    __syncthreads();
    #pragma unroll
    for (int kk = 0; kk < 16; ++kk){
      float4 a = *(const float4*)&As[kk][m0];
      float4 b = *(const float4*)&Bs[kk][n0];
      float aa[4] = {a.x,a.y,a.z,a.w};
      float bb[4] = {b.x,b.y,b.z,b.w};
      #pragma unroll
      for (int i = 0; i < 4; ++i)
        #pragma unroll
        for (int j = 0; j < 4; ++j)
          acc[i][j] += aa[i]*bb[j];
    }
  }
  float bof[4] = {0.f,0.f,0.f,0.f};
  if (c0 == 0){
    float4 bb = *(const float4*)(bo + (size_t)e*DM + col0 + n0);
    bof[0]=bb.x; bof[1]=bb.y; bof[2]=bb.z; bof[3]=bb.w;
  }
  #pragma unroll
  for (int i = 0; i < 4; ++i){
    int r = row0 + m0 + i;
    if (r < cnt){
      int tok = ridx[m0 + i];
      float g = rg[m0 + i];
      #pragma unroll
      for (int j = 0; j < 4; ++j)
        atomicAdd(Y + (size_t)tok*DM + col0 + n0 + j, (acc[i][j] + bof[j]) * g);
    }
  }
}

// ---------------- layernorm per token ----------------
__global__ __launch_bounds__(256)
void ln_k(const float* __restrict__ Y, const float* __restrict__ g,
          const float* __restrict__ bb, float* __restrict__ F)
{
  int t = blockIdx.x, tid = threadIdx.x;
  const float* yr = Y + (size_t)t * DM;
  float v0 = yr[tid], v1 = yr[tid + 256];
  __shared__ float red[8];
  int w = tid >> 6, lane = tid & 63;
  float s = v0 + v1;
  #pragma unroll
  for (int off = 32; off; off >>= 1) s += __shfl_xor(s, off, 64);
  if (lane == 0) red[w] = s;
  __syncthreads();
  float mu = (red[0]+red[1]+red[2]+red[3]) * (1.f/512.f);
  float d0 = v0 - mu, d1 = v1 - mu;
  float q2 = d0*d0 + d1*d1;
  #pragma unroll
  for (int off = 32; off; off >>= 1) q2 += __shfl_xor(q2, off, 64);
  if (lane == 0) red[4+w] = q2;
  __syncthreads();
  float var = (red[4]+red[5]+red[6]+red[7]) * (1.f/512.f);
  float r = 1.f / sqrtf(var + 1e-5f);
  F[(size_t)t*DM + tid]       = d0*r*g[tid]     + bb[tid];
  F[(size_t)t*DM + tid + 256] = d1*r*g[tid+256] + bb[tid+256];
}

// ---------------- global = sum over T of second_vector ----------------
__global__ void gsum_k(const float* __restrict__ sv, float* __restrict__ gb, float* __restrict__ gout){
  int i = blockIdx.x*256 + threadIdx.x;    // 16384 = 32*512
  int b = i >> 9, d = i & 511;
  const float* p = sv + (size_t)b*TT*DM + d;
  float s = 0.f;
  for (int t = 0; t < TT; ++t) s += p[(size_t)t*DM];
  gb[i] = s; gout[i] = s;
}

extern "C" void kernel_launch(void* const* d_in, const int* in_sizes, int n_in,
                              void* d_out, int out_size, void* d_ws, size_t ws_size,
                              hipStream_t stream)
{
  (void)in_sizes; (void)n_in; (void)out_size; (void)ws_size;
  const float* xin   = (const float*)d_in[0];
  const float* pembW = (const float*)d_in[1];
  const float* pembB = (const float*)d_in[2];
  const float* vecW  = (const float*)d_in[3];
  const float* vecB  = (const float*)d_in[4];
  const float* clsW  = (const float*)d_in[5];
  const float* clsB  = (const float*)d_in[6];
  float* out = (float*)d_out;

  // ---- workspace: ~16.1M f32 = 61.6 MiB total ----
  float* ws = (float*)d_ws;
  float* W    = ws;                    // h / q / o / first,second_vector (12.25 MB)
  float* X    = W + 3211264;           // xp / xbuf
  float* Y    = X + 3211264;           // k / moe accum y
  float* Z    = Y + 3211264;           // v / ln output f
  float* H1c  = Z + 3211264;           // 12544*FC f32 chunk (12.25 MB)
  float* patches = H1c;                // 6272*256 f32, aliased (dead before MoE)
  float* pe      = H1c + 1605632;      // 196*512, aliased (dead before MoE)
  float* gbv    = H1c + 3211264;       // 16384
  float* clsbuf = gbv + 16384;         // 16384
  float* tok_g  = clsbuf + 16384;      // 12544
  float* gate_c = tok_g + 12544;       // 12544
  int*   tok_e  = (int*)(gate_c + 12544); // 12544
  int*   idx_c  = tok_e + 12544;       // 12544
  int*   counts = idx_c + 12544;       // 8
  int*   offs   = counts + 8;          // 9
  int*   cursors= offs + 9;            // 8

  patchify_k<<<dim3(BT), dim3(256), 0, stream>>>(xin, patches);
  posenc_k<<<dim3(TT), dim3(512), 0, stream>>>(pe);
  // h = patches @ pemb_W + pemb_b + posenc   -> W
  gemm_f32<<<dim3(8,98), dim3(256), 0, stream>>>(patches, pembW, W, pembB, pe, nullptr, BT, DM, 256);

  for (int l = 0; l < 2; ++l){
    int base = 7 + 18*l;
    const float* pW  = (const float*)d_in[base+0];
    const float* pb  = (const float*)d_in[base+1];
    const float* Wq  = (const float*)d_in[base+2];
    const float* Wk  = (const float*)d_in[base+3];
    const float* Wv  = (const float*)d_in[base+4];
    const float* Wo  = (const float*)d_in[base+5];
    const float* bo  = (const float*)d_in[base+6];
    const float* rtW = (const float*)d_in[base+7];
    const float* rtb = (const float*)d_in[base+8];
    const float* rnW = (const float*)d_in[base+9];
    const float* rnb = (const float*)d_in[base+10];
    const float* eWi = (const float*)d_in[base+11];
    const float* ebi = (const float*)d_in[base+12];
    const float* eWo = (const float*)d_in[base+13];
    const float* ebo = (const float*)d_in[base+14];
    const float* lng = (const float*)d_in[base+15];
    const float* lnb = (const float*)d_in[base+16];
    const float* nz  = (const float*)d_in[base+17];

    // xp = h @ pW + pb        (W -> X; h dead afterwards)
    gemm_f32<<<dim3(8,98), dim3(256), 0, stream>>>(W, pW, X, pb, nullptr, nullptr, BT, DM, DM);
    // q,k,v                   (X -> W,Y,Z)
    gemm_f32<<<dim3(8,98), dim3(256), 0, stream>>>(X, Wq, W, nullptr, nullptr, nullptr, BT, DM, DM);
    gemm_f32<<<dim3(8,98), dim3(256), 0, stream>>>(X, Wk, Y, nullptr, nullptr, nullptr, BT, DM, DM);
    gemm_f32<<<dim3(8,98), dim3(256), 0, stream>>>(X, Wv, Z, nullptr, nullptr, nullptr, BT, DM, DM);
    // attention: o over q     (W,Y,Z -> W)
    attn_k<<<dim3(256), dim3(256), 0, stream>>>(W, Y, Z, W);
    // xbuf = o @ Wo + bo      (W -> X; xp dead)
    gemm_f32<<<dim3(8,98), dim3(256), 0, stream>>>(W, Wo, X, bo, nullptr, nullptr, BT, DM, DM);
    // router on X
    hipMemsetAsync(counts, 0, 8*sizeof(int), stream);
    router_k<<<dim3(BT/4), dim3(256), 0, stream>>>(X, rtW, rtb, rnW, rnb, nz, tok_e, tok_g, counts);
    scan_k<<<dim3(1), dim3(64), 0, stream>>>(counts, offs, cursors);
    assign_k<<<dim3((BT+255)/256), dim3(256), 0, stream>>>(tok_e, tok_g, cursors, idx_c, gate_c);
    // experts, FF chunked; y accumulates in Y (k dead)
    hipMemsetAsync(Y, 0, (size_t)3211264*sizeof(float), stream);
    for (int c0 = 0; c0 < FFD; c0 += FC){
      gemm_moe1<<<dim3(FC/64, 98, NE), dim3(256), 0, stream>>>(X, eWi, ebi, offs, idx_c, H1c, c0);
      gemm_moe2<<<dim3(DM/64, 98, NE), dim3(256), 0, stream>>>(H1c, eWo, ebo, offs, idx_c, gate_c, Y, c0);
    }
    // f = LN(y)               (Y -> Z; v dead)
    ln_k<<<dim3(BT), dim3(256), 0, stream>>>(Y, lng, lnb, Z);
    // first/second_vector = f @ vec_W + vec_b   (Z -> W, + f32 mirror to out)
    float* mirror = out + (size_t)l * 3211264;
    gemm_f32<<<dim3(8,98), dim3(256), 0, stream>>>(Z, vecW, W, vecB, nullptr, mirror, BT, DM, DM);
  }

  // global_vector = sum over patches of second_vector (in W); cls = global @ cls_W + cls_b
  gsum_k<<<dim3(64), dim3(256), 0, stream>>>(W, gbv, out + 6422528);
  gemm_f32<<<dim3(8,1), dim3(256), 0, stream>>>(gbv, clsW, clsbuf, clsB, nullptr, out + 6438912, 32, DM, DM);
}

// Round 4
// 4412.841 us; speedup vs baseline: 1.0891x; 1.0891x over previous
//
#include <hip/hip_runtime.h>

#define BT 6272      // B*T = 32*196
#define TT 196
#define DM 512
#define FFD 2048
#define NE 8
#define FC 256       // MoE hidden chunk
#define ABUF 3211264 // activation buffer elems (6272*512)

// ---------------- patchify: x[B,1,224,224] f32 -> patches[BT,256] f32 ----------------
__global__ void patchify_k(const float* __restrict__ x, float* __restrict__ out){
  int bt = blockIdx.x;
  int t = bt % TT, b = bt / TT;
  int pd = threadIdx.x;
  int g1 = t / 14, g2 = t % 14, p1 = pd >> 4, p2 = pd & 15;
  int src = (b*224 + g1*16 + p1)*224 + g2*16 + p2;
  out[(size_t)bt*256 + pd] = x[src];
}

// ---------------- posenc[196,512] f32 ----------------
__global__ void posenc_k(float* __restrict__ pe){
  int t = blockIdx.x, c = threadIdx.x;
  int m2 = c & ~1;
  double ang = (double)t * pow(10000.0, -(double)m2 / 512.0);
  double vv = (c & 1) ? cos(ang) : sin(ang);
  pe[t*DM + c] = (float)vv;
}

// ---------------- 128x128 fp32 GEMM, 256 thr, 8x8/thread, reg prefetch ----------------
__global__ __launch_bounds__(256)
void gemm128(const float* __restrict__ A, const float* __restrict__ B,
             float* __restrict__ C, const float* __restrict__ bias,
             const float* __restrict__ pe, float* __restrict__ mirror,
             int N, int K)
{
  __shared__ float As[16][132];
  __shared__ float Bs[16][132];
  int tid = threadIdx.x;
  int row0 = blockIdx.y << 7, col0 = blockIdx.x << 7;
  int ar = tid >> 1, ak = (tid & 1) << 3;
  int bk = tid >> 4, bn = (tid & 15) << 3;
  int m0 = (tid >> 4) << 3, n0 = (tid & 15) << 3;
  const float* Ap = A + (size_t)(row0 + ar) * K + ak;
  const float* Bp = B + (size_t)bk * N + col0 + bn;
  float4 a0 = *(const float4*)(Ap);
  float4 a1 = *(const float4*)(Ap + 4);
  float4 b0 = *(const float4*)(Bp);
  float4 b1 = *(const float4*)(Bp + 4);
  float acc[8][8] = {};
  for (int k0 = 0; k0 < K; k0 += 16){
    __syncthreads();
    As[ak+0][ar]=a0.x; As[ak+1][ar]=a0.y; As[ak+2][ar]=a0.z; As[ak+3][ar]=a0.w;
    As[ak+4][ar]=a1.x; As[ak+5][ar]=a1.y; As[ak+6][ar]=a1.z; As[ak+7][ar]=a1.w;
    *(float4*)&Bs[bk][bn]   = b0;
    *(float4*)&Bs[bk][bn+4] = b1;
    __syncthreads();
    if (k0 + 16 < K){
      a0 = *(const float4*)(Ap + k0 + 16);
      a1 = *(const float4*)(Ap + k0 + 20);
      b0 = *(const float4*)(Bp + (size_t)(k0+16)*N);
      b1 = *(const float4*)(Bp + (size_t)(k0+16)*N + 4);
    }
    #pragma unroll
    for (int kk = 0; kk < 16; ++kk){
      float4 x0 = *(const float4*)&As[kk][m0];
      float4 x1 = *(const float4*)&As[kk][m0+4];
      float4 y0 = *(const float4*)&Bs[kk][n0];
      float4 y1 = *(const float4*)&Bs[kk][n0+4];
      float xa[8] = {x0.x,x0.y,x0.z,x0.w,x1.x,x1.y,x1.z,x1.w};
      float yb[8] = {y0.x,y0.y,y0.z,y0.w,y1.x,y1.y,y1.z,y1.w};
      #pragma unroll
      for (int i = 0; i < 8; ++i)
        #pragma unroll
        for (int j = 0; j < 8; ++j)
          acc[i][j] += xa[i]*yb[j];
    }
  }
  float badd[8] = {};
  if (bias){
    float4 v0 = *(const float4*)(bias + col0 + n0);
    float4 v1 = *(const float4*)(bias + col0 + n0 + 4);
    badd[0]=v0.x; badd[1]=v0.y; badd[2]=v0.z; badd[3]=v0.w;
    badd[4]=v1.x; badd[5]=v1.y; badd[6]=v1.z; badd[7]=v1.w;
  }
  #pragma unroll
  for (int i = 0; i < 8; ++i){
    int gr = row0 + m0 + i;
    float r[8];
    #pragma unroll
    for (int j = 0; j < 8; ++j) r[j] = acc[i][j] + badd[j];
    if (pe){
      const float* pv = pe + (size_t)(gr % TT)*DM + col0 + n0;
      #pragma unroll
      for (int j = 0; j < 8; ++j) r[j] += pv[j];
    }
    float* cp = C + (size_t)gr*N + col0 + n0;
    *(float4*)cp       = make_float4(r[0],r[1],r[2],r[3]);
    *(float4*)(cp + 4) = make_float4(r[4],r[5],r[6],r[7]);
    if (mirror){
      float* mp = mirror + (size_t)gr*N + col0 + n0;
      *(float4*)mp       = make_float4(r[0],r[1],r[2],r[3]);
      *(float4*)(mp + 4) = make_float4(r[4],r[5],r[6],r[7]);
    }
  }
}

// ---------------- old 64x64 GEMM (kept for the tiny cls matmul, M=32) ----------------
__global__ __launch_bounds__(256)
void gemm_f32(const float* __restrict__ A, const float* __restrict__ Bw,
              float* __restrict__ C, const float* __restrict__ bias,
              float* __restrict__ obf, int M, int N, int K)
{
  __shared__ float As[16][68];
  __shared__ float Bs[16][68];
  int tid = threadIdx.x;
  int row0 = blockIdx.y << 6, col0 = blockIdx.x << 6;
  int ar = tid >> 2, ak = (tid & 3) << 2;
  int bk = tid >> 4, bn = (tid & 15) << 2;
  int n0 = (tid & 15) << 2, m0 = (tid >> 4) << 2;
  float acc[4][4] = {};
  bool arow_ok = (row0 + ar) < M;
  const float* Aldg = A + (size_t)(row0 + ar) * K + ak;
  const float* Bldg = Bw + (size_t)bk * N + col0 + bn;
  for (int k0 = 0; k0 < K; k0 += 16){
    float4 av = make_float4(0.f,0.f,0.f,0.f);
    if (arow_ok) av = *(const float4*)(Aldg + k0);
    float4 bv = *(const float4*)(Bldg + (size_t)k0 * N);
    __syncthreads();
    As[ak+0][ar]=av.x; As[ak+1][ar]=av.y; As[ak+2][ar]=av.z; As[ak+3][ar]=av.w;
    *(float4*)&Bs[bk][bn] = bv;
    __syncthreads();
    #pragma unroll
    for (int kk = 0; kk < 16; ++kk){
      float4 a = *(const float4*)&As[kk][m0];
      float4 b = *(const float4*)&Bs[kk][n0];
      float aa[4] = {a.x,a.y,a.z,a.w};
      float bb[4] = {b.x,b.y,b.z,b.w};
      #pragma unroll
      for (int i = 0; i < 4; ++i)
        #pragma unroll
        for (int j = 0; j < 4; ++j)
          acc[i][j] += aa[i]*bb[j];
    }
  }
  float4 badd = make_float4(0.f,0.f,0.f,0.f);
  if (bias) badd = *(const float4*)(bias + col0 + n0);
  #pragma unroll
  for (int i = 0; i < 4; ++i){
    int gr = row0 + m0 + i;
    if (gr < M){
      float4 r = make_float4(acc[i][0]+badd.x, acc[i][1]+badd.y, acc[i][2]+badd.z, acc[i][3]+badd.w);
      *(float4*)(C + (size_t)gr*N + col0 + n0) = r;
      if (obf) *(float4*)(obf + (size_t)gr*N + col0 + n0) = r;
    }
  }
}

// ---------------- flash-style causal attention: block = (q-tile 64) x (b,h) ----------------
// o may alias q: each block reads only its own q-tile (staged before any o store). [4x4 frags]
__global__ __launch_bounds__(256)
void fattn_k(const float* q, const float* __restrict__ k,
             const float* __restrict__ v, float* o)
{
  __shared__ float Qt[64][68];   // Q^T [d][row]
  __shared__ float KP[64][68];   // K^T [d][j] during S; P^T [j][row] during PV
  __shared__ float Vs[64][68];   // V   [j][d]
  int qt = blockIdx.x, bh = blockIdx.y;
  int b = bh >> 3, h = bh & 7;
  size_t base = (size_t)b * TT * DM + h * 64;
  int tid = threadIdx.x;
  int ty = tid >> 4, tx = tid & 15;
  int m0 = ty << 2, n0 = tx << 2;
  // stage Q^T
  {
    int r = tid >> 2, dd = (tid & 3) << 4;
    int qrow = qt*64 + r;
    const float* qp = q + base + (size_t)(qrow < TT ? qrow : TT-1) * DM;
    #pragma unroll
    for (int u = 0; u < 4; ++u){
      float4 t4 = *(const float4*)(qp + dd + u*4);
      Qt[dd+u*4+0][r]=t4.x; Qt[dd+u*4+1][r]=t4.y; Qt[dd+u*4+2][r]=t4.z; Qt[dd+u*4+3][r]=t4.w;
    }
  }
  float o_acc[4][4] = {};
  float m_i[4], l_i[4];
  #pragma unroll
  for (int i = 0; i < 4; ++i){ m_i[i] = -3e38f; l_i[i] = 0.f; }
  int ktiles = qt + 1;
  for (int kt = 0; kt < ktiles; ++kt){
    __syncthreads();
    {
      int r = tid >> 2, dd = (tid & 3) << 4;
      int jrow = kt*64 + r;
      int jc = jrow < TT ? jrow : TT-1;
      const float* kp = k + base + (size_t)jc * DM;
      const float* vp = v + base + (size_t)jc * DM;
      #pragma unroll
      for (int u = 0; u < 4; ++u){
        float4 t4 = *(const float4*)(kp + dd + u*4);
        KP[dd+u*4+0][r]=t4.x; KP[dd+u*4+1][r]=t4.y; KP[dd+u*4+2][r]=t4.z; KP[dd+u*4+3][r]=t4.w;
        *(float4*)&Vs[r][dd + u*4] = *(const float4*)(vp + dd + u*4);
      }
    }
    __syncthreads();
    // S-tile
    float s[4][4] = {};
    #pragma unroll 8
    for (int d = 0; d < 64; ++d){
      float4 a = *(const float4*)&Qt[d][m0];
      float4 bb = *(const float4*)&KP[d][n0];
      float xa[4] = {a.x,a.y,a.z,a.w};
      float yb[4] = {bb.x,bb.y,bb.z,bb.w};
      #pragma unroll
      for (int i = 0; i < 4; ++i)
        #pragma unroll
        for (int j = 0; j < 4; ++j)
          s[i][j] += xa[i]*yb[j];
    }
    int qrow0 = qt*64 + m0, jcol0 = kt*64 + n0;
    #pragma unroll
    for (int i = 0; i < 4; ++i)
      #pragma unroll
      for (int j = 0; j < 4; ++j){
        int jj = jcol0 + j;
        s[i][j] = (jj <= qrow0 + i && jj < TT) ? s[i][j]*0.125f : -3e38f;
      }
    // online softmax (row reductions over tx: lanes xor 1,2,4,8 stay in row-group)
    float p[4][4];
    #pragma unroll
    for (int i = 0; i < 4; ++i){
      float mx = fmaxf(fmaxf(s[i][0],s[i][1]), fmaxf(s[i][2],s[i][3]));
      #pragma unroll
      for (int off = 1; off < 16; off <<= 1) mx = fmaxf(mx, __shfl_xor(mx, off, 64));
      float mnew = fmaxf(m_i[i], mx);
      float al = expf(m_i[i] - mnew);
      l_i[i] *= al;
      #pragma unroll
      for (int c = 0; c < 4; ++c) o_acc[i][c] *= al;
      float ps = 0.f;
      #pragma unroll
      for (int j = 0; j < 4; ++j){ p[i][j] = expf(s[i][j] - mnew); ps += p[i][j]; }
      #pragma unroll
      for (int off = 1; off < 16; off <<= 1) ps += __shfl_xor(ps, off, 64);
      l_i[i] += ps;
      m_i[i] = mnew;
    }
    __syncthreads();          // all S reads of KP done
    #pragma unroll
    for (int i = 0; i < 4; ++i)
      #pragma unroll
      for (int j = 0; j < 4; ++j)
        KP[n0 + j][m0 + i] = p[i][j];   // store P^T
    __syncthreads();
    // PV
    #pragma unroll 8
    for (int jj = 0; jj < 64; ++jj){
      float4 a = *(const float4*)&KP[jj][m0];
      float4 bb = *(const float4*)&Vs[jj][n0];
      float xa[4] = {a.x,a.y,a.z,a.w};
      float yb[4] = {bb.x,bb.y,bb.z,bb.w};
      #pragma unroll
      for (int i = 0; i < 4; ++i)
        #pragma unroll
        for (int c = 0; c < 4; ++c)
          o_acc[i][c] += xa[i]*yb[c];
    }
  }
  #pragma unroll
  for (int i = 0; i < 4; ++i){
    int qrow = qt*64 + m0 + i;
    if (qrow < TT){
      float inv = 1.f / l_i[i];
      float4 r = make_float4(o_acc[i][0]*inv, o_acc[i][1]*inv, o_acc[i][2]*inv, o_acc[i][3]*inv);
      *(float4*)(o + base + (size_t)qrow*DM + n0) = r;
    }
  }
}

// ---------------- router ----------------
__global__ __launch_bounds__(256)
void router_k(const float* __restrict__ X, const float* __restrict__ rtW, const float* __restrict__ rtb,
              const float* __restrict__ rnW, const float* __restrict__ rnb, const float* __restrict__ nz,
              int* __restrict__ tok_e, float* __restrict__ tok_g, int* __restrict__ counts)
{
  int w = threadIdx.x >> 6, lane = threadIdx.x & 63;
  int t = (blockIdx.x << 2) + w;
  const float* xr = X + (size_t)t * DM;
  float at[8] = {}, an[8] = {};
  #pragma unroll
  for (int u = 0; u < 8; ++u){
    int d = (u<<6) + lane;
    float xv = xr[d];
    float4 wt0 = *(const float4*)(rtW + (size_t)d*8);
    float4 wt1 = *(const float4*)(rtW + (size_t)d*8 + 4);
    float4 wn0 = *(const float4*)(rnW + (size_t)d*8);
    float4 wn1 = *(const float4*)(rnW + (size_t)d*8 + 4);
    at[0]+=xv*wt0.x; at[1]+=xv*wt0.y; at[2]+=xv*wt0.z; at[3]+=xv*wt0.w;
    at[4]+=xv*wt1.x; at[5]+=xv*wt1.y; at[6]+=xv*wt1.z; at[7]+=xv*wt1.w;
    an[0]+=xv*wn0.x; an[1]+=xv*wn0.y; an[2]+=xv*wn0.z; an[3]+=xv*wn0.w;
    an[4]+=xv*wn1.x; an[5]+=xv*wn1.y; an[6]+=xv*wn1.z; an[7]+=xv*wn1.w;
  }
  #pragma unroll
  for (int off = 32; off; off >>= 1){
    #pragma unroll
    for (int e = 0; e < 8; ++e){
      at[e] += __shfl_xor(at[e], off, 64);
      an[e] += __shfl_xor(an[e], off, 64);
    }
  }
  if (lane == 0){
    float ns[8];
    #pragma unroll
    for (int e = 0; e < 8; ++e){
      float lt = at[e] + rtb[e];
      float ln_ = an[e] + rnb[e];
      float sp = (ln_ > 0.f) ? (ln_ + log1pf(expf(-ln_))) : log1pf(expf(ln_));
      ns[e] = lt + nz[(size_t)t*8 + e] * sp;
    }
    int i1 = 0; float n1 = ns[0];
    #pragma unroll
    for (int e = 1; e < 8; ++e) if (ns[e] > n1){ n1 = ns[e]; i1 = e; }
    int i2 = -1; float n2 = -3e38f;
    #pragma unroll
    for (int e = 0; e < 8; ++e) if (e != i1 && ns[e] > n2){ n2 = ns[e]; i2 = e; }
    float ex = expf(n2 - n1);
    float inv = 1.f / (1.f + ex);
    tok_e[t*2]   = i1; tok_g[t*2]   = inv;
    tok_e[t*2+1] = i2; tok_g[t*2+1] = ex * inv;
    atomicAdd(counts + i1, 1);
    atomicAdd(counts + i2, 1);
  }
}

__global__ void scan_k(const int* __restrict__ counts, int* __restrict__ offs, int* __restrict__ cursors){
  if (threadIdx.x == 0){
    int s = 0;
    for (int e = 0; e < NE; ++e){ offs[e] = s; cursors[e] = s; s += counts[e]; }
    offs[NE] = s;
  }
}

__global__ void assign_k(const int* __restrict__ tok_e, int* __restrict__ cursors,
                         int* __restrict__ idx_c, int* __restrict__ tok_slot){
  int t = blockIdx.x*256 + threadIdx.x;
  if (t >= BT) return;
  #pragma unroll
  for (int kk = 0; kk < 2; ++kk){
    int e = tok_e[t*2+kk];
    int p = atomicAdd(cursors + e, 1);
    idx_c[p] = t;
    tok_slot[t*2+kk] = p;
  }
}

// ---------------- MoE GEMM1 (128x128, gathered rows): H1c[slot][0..FC) chunk ----------------
__global__ __launch_bounds__(256)
void moe1_128(const float* __restrict__ X, const float* __restrict__ Wi,
              const float* __restrict__ bi, const int* __restrict__ offs,
              const int* __restrict__ idx_c, float* __restrict__ H1, int c0)
{
  int e = blockIdx.z;
  int base = offs[e], cnt = offs[e+1] - base;
  int row0 = blockIdx.y << 7;
  if (row0 >= cnt) return;
  int col0 = blockIdx.x << 7;
  __shared__ float As[16][132];
  __shared__ float Bs[16][132];
  int tid = threadIdx.x;
  int ar = tid >> 1, ak = (tid & 1) << 3;
  int bk = tid >> 4, bn = (tid & 15) << 3;
  int m0 = (tid >> 4) << 3, n0 = (tid & 15) << 3;
  int rr = (row0 + ar < cnt) ? idx_c[base + row0 + ar] : -1;
  const float* Ap = (rr >= 0) ? (X + (size_t)rr*DM + ak) : nullptr;
  const float* Bp = Wi + (size_t)e * DM * FFD + c0 + (size_t)bk * FFD + col0 + bn;
  float4 zero = make_float4(0.f,0.f,0.f,0.f);
  float4 a0 = Ap ? *(const float4*)(Ap)     : zero;
  float4 a1 = Ap ? *(const float4*)(Ap + 4) : zero;
  float4 b0 = *(const float4*)(Bp);
  float4 b1 = *(const float4*)(Bp + 4);
  float acc[8][8] = {};
  for (int k0 = 0; k0 < DM; k0 += 16){
    __syncthreads();
    As[ak+0][ar]=a0.x; As[ak+1][ar]=a0.y; As[ak+2][ar]=a0.z; As[ak+3][ar]=a0.w;
    As[ak+4][ar]=a1.x; As[ak+5][ar]=a1.y; As[ak+6][ar]=a1.z; As[ak+7][ar]=a1.w;
    *(float4*)&Bs[bk][bn]   = b0;
    *(float4*)&Bs[bk][bn+4] = b1;
    __syncthreads();
    if (k0 + 16 < DM){
      if (Ap){ a0 = *(const float4*)(Ap + k0 + 16); a1 = *(const float4*)(Ap + k0 + 20); }
      b0 = *(const float4*)(Bp + (size_t)(k0+16)*FFD);
      b1 = *(const float4*)(Bp + (size_t)(k0+16)*FFD + 4);
    }
    #pragma unroll
    for (int kk = 0; kk < 16; ++kk){
      float4 x0 = *(const float4*)&As[kk][m0];
      float4 x1 = *(const float4*)&As[kk][m0+4];
      float4 y0 = *(const float4*)&Bs[kk][n0];
      float4 y1 = *(const float4*)&Bs[kk][n0+4];
      float xa[8] = {x0.x,x0.y,x0.z,x0.w,x1.x,x1.y,x1.z,x1.w};
      float yb[8] = {y0.x,y0.y,y0.z,y0.w,y1.x,y1.y,y1.z,y1.w};
      #pragma unroll
      for (int i = 0; i < 8; ++i)
        #pragma unroll
        for (int j = 0; j < 8; ++j)
          acc[i][j] += xa[i]*yb[j];
    }
  }
  float bb8[8];
  {
    const float* bp = bi + (size_t)e*FFD + c0 + col0 + n0;
    #pragma unroll
    for (int j = 0; j < 8; ++j) bb8[j] = bp[j];
  }
  #pragma unroll
  for (int i = 0; i < 8; ++i){
    int r = row0 + m0 + i;
    if (r < cnt){
      float* hp = H1 + (size_t)(base + r)*FC + col0 + n0;
      *(float4*)hp     = make_float4(fmaxf(acc[i][0]+bb8[0],0.f), fmaxf(acc[i][1]+bb8[1],0.f),
                                     fmaxf(acc[i][2]+bb8[2],0.f), fmaxf(acc[i][3]+bb8[3],0.f));
      *(float4*)(hp+4) = make_float4(fmaxf(acc[i][4]+bb8[4],0.f), fmaxf(acc[i][5]+bb8[5],0.f),
                                     fmaxf(acc[i][6]+bb8[6],0.f), fmaxf(acc[i][7]+bb8[7],0.f));
    }
  }
}

// ---------------- MoE GEMM2 (128x128, slot-space, no atomics): Yexp[slot] (+)= H1c @ Wo_chunk ----------------
__global__ __launch_bounds__(256)
void moe2_128(const float* __restrict__ H1, const float* __restrict__ Wo,
              const float* __restrict__ bo, const int* __restrict__ offs,
              float* __restrict__ Ye, int c0)
{
  int e = blockIdx.z;
  int base = offs[e], cnt = offs[e+1] - base;
  int row0 = blockIdx.y << 7;
  if (row0 >= cnt) return;
  int col0 = blockIdx.x << 7;
  __shared__ float As[16][132];
  __shared__ float Bs[16][132];
  int tid = threadIdx.x;
  int ar = tid >> 1, ak = (tid & 1) << 3;
  int bk = tid >> 4, bn = (tid & 15) << 3;
  int m0 = (tid >> 4) << 3, n0 = (tid & 15) << 3;
  bool arow_ok = (row0 + ar) < cnt;
  const float* Ap = H1 + (size_t)(base + row0 + ar)*FC + ak;
  const float* Bp = Wo + (size_t)e * FFD * DM + (size_t)(c0 + bk) * DM + col0 + bn;
  float4 zero = make_float4(0.f,0.f,0.f,0.f);
  float4 a0 = arow_ok ? *(const float4*)(Ap)     : zero;
  float4 a1 = arow_ok ? *(const float4*)(Ap + 4) : zero;
  float4 b0 = *(const float4*)(Bp);
  float4 b1 = *(const float4*)(Bp + 4);
  float acc[8][8] = {};
  for (int k0 = 0; k0 < FC; k0 += 16){
    __syncthreads();
    As[ak+0][ar]=a0.x; As[ak+1][ar]=a0.y; As[ak+2][ar]=a0.z; As[ak+3][ar]=a0.w;
    As[ak+4][ar]=a1.x; As[ak+5][ar]=a1.y; As[ak+6][ar]=a1.z; As[ak+7][ar]=a1.w;
    *(float4*)&Bs[bk][bn]   = b0;
    *(float4*)&Bs[bk][bn+4] = b1;
    __syncthreads();
    if (k0 + 16 < FC){
      if (arow_ok){ a0 = *(const float4*)(Ap + k0 + 16); a1 = *(const float4*)(Ap + k0 + 20); }
      b0 = *(const float4*)(Bp + (size_t)(k0+16)*DM);
      b1 = *(const float4*)(Bp + (size_t)(k0+16)*DM + 4);
    }
    #pragma unroll
    for (int kk = 0; kk < 16; ++kk){
      float4 x0 = *(const float4*)&As[kk][m0];
      float4 x1 = *(const float4*)&As[kk][m0+4];
      float4 y0 = *(const float4*)&Bs[kk][n0];
      float4 y1 = *(const float4*)&Bs[kk][n0+4];
      float xa[8] = {x0.x,x0.y,x0.z,x0.w,x1.x,x1.y,x1.z,x1.w};
      float yb[8] = {y0.x,y0.y,y0.z,y0.w,y1.x,y1.y,y1.z,y1.w};
      #pragma unroll
      for (int i = 0; i < 8; ++i)
        #pragma unroll
        for (int j = 0; j < 8; ++j)
          acc[i][j] += xa[i]*yb[j];
    }
  }
  #pragma unroll
  for (int i = 0; i < 8; ++i){
    int r = row0 + m0 + i;
    if (r < cnt){
      float* yp = Ye + (size_t)(base + r)*DM + col0 + n0;
      if (c0 == 0){
        const float* bp = bo + (size_t)e*DM + col0 + n0;
        *(float4*)yp     = make_float4(acc[i][0]+bp[0], acc[i][1]+bp[1], acc[i][2]+bp[2], acc[i][3]+bp[3]);
        *(float4*)(yp+4) = make_float4(acc[i][4]+bp[4], acc[i][5]+bp[5], acc[i][6]+bp[6], acc[i][7]+bp[7]);
      } else {
        float4 o0 = *(const float4*)yp;
        float4 o1 = *(const float4*)(yp+4);
        *(float4*)yp     = make_float4(o0.x+acc[i][0], o0.y+acc[i][1], o0.z+acc[i][2], o0.w+acc[i][3]);
        *(float4*)(yp+4) = make_float4(o1.x+acc[i][4], o1.y+acc[i][5], o1.z+acc[i][6], o1.w+acc[i][7]);
      }
    }
  }
}

// ---------------- gated combine + layernorm ----------------
__global__ __launch_bounds__(256)
void combine_ln_k(const float* __restrict__ Ye, const int* __restrict__ tok_slot,
                  const float* __restrict__ tok_g, const float* __restrict__ g,
                  const float* __restrict__ bb, float* __restrict__ F)
{
  int t = blockIdx.x, tid = threadIdx.x;
  int s1 = tok_slot[t*2], s2 = tok_slot[t*2+1];
  float g1 = tok_g[t*2], g2 = tok_g[t*2+1];
  const float* y1 = Ye + (size_t)s1*DM;
  const float* y2 = Ye + (size_t)s2*DM;
  float v0 = g1*y1[tid]     + g2*y2[tid];
  float v1 = g1*y1[tid+256] + g2*y2[tid+256];
  __shared__ float red[8];
  int w = tid >> 6, lane = tid & 63;
  float s = v0 + v1;
  #pragma unroll
  for (int off = 32; off; off >>= 1) s += __shfl_xor(s, off, 64);
  if (lane == 0) red[w] = s;
  __syncthreads();
  float mu = (red[0]+red[1]+red[2]+red[3]) * (1.f/512.f);
  float d0 = v0 - mu, d1 = v1 - mu;
  float q2 = d0*d0 + d1*d1;
  #pragma unroll
  for (int off = 32; off; off >>= 1) q2 += __shfl_xor(q2, off, 64);
  if (lane == 0) red[4+w] = q2;
  __syncthreads();
  float var = (red[4]+red[5]+red[6]+red[7]) * (1.f/512.f);
  float r = 1.f / sqrtf(var + 1e-5f);
  F[(size_t)t*DM + tid]       = d0*r*g[tid]     + bb[tid];
  F[(size_t)t*DM + tid + 256] = d1*r*g[tid+256] + bb[tid+256];
}

// ---------------- global = sum over T of second_vector ----------------
__global__ void gsum_k(const float* __restrict__ sv, float* __restrict__ gb, float* __restrict__ gout){
  int i = blockIdx.x*256 + threadIdx.x;
  int b = i >> 9, d = i & 511;
  const float* p = sv + (size_t)b*TT*DM + d;
  float s = 0.f;
  for (int t = 0; t < TT; ++t) s += p[(size_t)t*DM];
  gb[i] = s; gout[i] = s;
}

extern "C" void kernel_launch(void* const* d_in, const int* in_sizes, int n_in,
                              void* d_out, int out_size, void* d_ws, size_t ws_size,
                              hipStream_t stream)
{
  (void)in_sizes; (void)n_in; (void)out_size; (void)ws_size;
  const float* xin   = (const float*)d_in[0];
  const float* pembW = (const float*)d_in[1];
  const float* pembB = (const float*)d_in[2];
  const float* vecW  = (const float*)d_in[3];
  const float* vecB  = (const float*)d_in[4];
  const float* clsW  = (const float*)d_in[5];
  const float* clsB  = (const float*)d_in[6];
  float* out = (float*)d_out;

  // ---- workspace (same 61.6 MiB footprint as the known-good R3 layout) ----
  float* ws = (float*)d_ws;
  float* A0   = ws;
  float* A1   = A0 + ABUF;
  float* A2   = A1 + ABUF;           // also Yexp lower half (A2|A3 contiguous)
  float* A3   = A2 + ABUF;
  float* H1c  = A3 + ABUF;           // 12544*FC chunk == ABUF elems
  float* Yexp = A2;                  // 12544*512 spans A2..A3
  float* patches = H1c;              // aliases (dead before MoE)
  float* pe      = H1c + 1605632;
  float* gbv    = H1c + ABUF;
  float* clsbuf = gbv + 16384;
  float* tok_g  = clsbuf + 16384;
  int*   tok_e  = (int*)(tok_g + 12544);
  int*   tok_slot = tok_e + 12544;
  int*   idx_c  = tok_slot + 12544;
  int*   counts = idx_c + 12544;
  int*   offs   = counts + 8;
  int*   cursors= offs + 9;

  patchify_k<<<dim3(BT), dim3(256), 0, stream>>>(xin, patches);
  posenc_k<<<dim3(TT), dim3(512), 0, stream>>>(pe);
  // h = patches @ pemb_W + pemb_b + posenc  -> A1
  gemm128<<<dim3(4,49), dim3(256), 0, stream>>>(patches, pembW, A1, pembB, pe, nullptr, DM, 256);

  float* P = A1;  // layer input
  float* Q = A0;  // partner
  for (int l = 0; l < 2; ++l){
    int base = 7 + 18*l;
    const float* pW  = (const float*)d_in[base+0];
    const float* pb  = (const float*)d_in[base+1];
    const float* Wq  = (const float*)d_in[base+2];
    const float* Wk  = (const float*)d_in[base+3];
    const float* Wv  = (const float*)d_in[base+4];
    const float* Wo  = (const float*)d_in[base+5];
    const float* bo  = (const float*)d_in[base+6];
    const float* rtW = (const float*)d_in[base+7];
    const float* rtb = (const float*)d_in[base+8];
    const float* rnW = (const float*)d_in[base+9];
    const float* rnb = (const float*)d_in[base+10];
    const float* eWi = (const float*)d_in[base+11];
    const float* ebi = (const float*)d_in[base+12];
    const float* eWo = (const float*)d_in[base+13];
    const float* ebo = (const float*)d_in[base+14];
    const float* lng = (const float*)d_in[base+15];
    const float* lnb = (const float*)d_in[base+16];
    const float* nz  = (const float*)d_in[base+17];

    // xp = P @ pW + pb  -> Q
    gemm128<<<dim3(4,49), dim3(256), 0, stream>>>(P, pW, Q, pb, nullptr, nullptr, DM, DM);
    // q,k,v : Q -> P, A2, A3
    gemm128<<<dim3(4,49), dim3(256), 0, stream>>>(Q, Wq, P, nullptr, nullptr, nullptr, DM, DM);
    gemm128<<<dim3(4,49), dim3(256), 0, stream>>>(Q, Wk, A2, nullptr, nullptr, nullptr, DM, DM);
    gemm128<<<dim3(4,49), dim3(256), 0, stream>>>(Q, Wv, A3, nullptr, nullptr, nullptr, DM, DM);
    // attention (o over q in P)
    fattn_k<<<dim3(4,256), dim3(256), 0, stream>>>(P, A2, A3, P);
    // xbuf = o @ Wo + bo -> Q
    gemm128<<<dim3(4,49), dim3(256), 0, stream>>>(P, Wo, Q, bo, nullptr, nullptr, DM, DM);
    // router on Q
    hipMemsetAsync(counts, 0, 8*sizeof(int), stream);
    router_k<<<dim3(BT/4), dim3(256), 0, stream>>>(Q, rtW, rtb, rnW, rnb, nz, tok_e, tok_g, counts);
    scan_k<<<dim3(1), dim3(64), 0, stream>>>(counts, offs, cursors);
    assign_k<<<dim3((BT+255)/256), dim3(256), 0, stream>>>(tok_e, cursors, idx_c, tok_slot);
    // experts, FF-chunked; Yexp accumulates per-slot (no atomics)
    for (int c0 = 0; c0 < FFD; c0 += FC){
      moe1_128<<<dim3(FC/128, 49, NE), dim3(256), 0, stream>>>(Q, eWi, ebi, offs, idx_c, H1c, c0);
      moe2_128<<<dim3(DM/128, 49, NE), dim3(256), 0, stream>>>(H1c, eWo, ebo, offs, Yexp, c0);
    }
    // gated combine + LN -> P
    combine_ln_k<<<dim3(BT), dim3(256), 0, stream>>>(Yexp, tok_slot, tok_g, lng, lnb, P);
    // first/second_vector = P @ vec_W + vec_b -> Q (+ mirror to out)
    float* mirror = out + (size_t)l * ABUF;
    gemm128<<<dim3(4,49), dim3(256), 0, stream>>>(P, vecW, Q, vecB, nullptr, mirror, DM, DM);
    // rotate
    float* tmp = P; P = Q; Q = tmp;
  }

  // P now holds second_vector
  gsum_k<<<dim3(64), dim3(256), 0, stream>>>(P, gbv, out + 2*ABUF);
  gemm_f32<<<dim3(8,1), dim3(256), 0, stream>>>(gbv, clsW, clsbuf, clsB, out + 2*ABUF + 16384, 32, DM, DM);
}

// Round 5
// 2882.963 us; speedup vs baseline: 1.6671x; 1.5307x over previous
//
#include <hip/hip_runtime.h>

#define BT 6272      // B*T = 32*196
#define TT 196
#define DM 512
#define FFD 2048
#define NE 8
#define ABUF 3211264 // activation buffer elems (6272*512)

// ---------------- patchify: x[B,1,224,224] f32 -> patches[BT,256] f32 ----------------
__global__ void patchify_k(const float* __restrict__ x, float* __restrict__ out){
  int bt = blockIdx.x;
  int t = bt % TT, b = bt / TT;
  int pd = threadIdx.x;
  int g1 = t / 14, g2 = t % 14, p1 = pd >> 4, p2 = pd & 15;
  int src = (b*224 + g1*16 + p1)*224 + g2*16 + p2;
  out[(size_t)bt*256 + pd] = x[src];
}

// ---------------- posenc[196,512] f32 ----------------
__global__ void posenc_k(float* __restrict__ pe){
  int t = blockIdx.x, c = threadIdx.x;
  int m2 = c & ~1;
  double ang = (double)t * pow(10000.0, -(double)m2 / 512.0);
  double vv = (c & 1) ? cos(ang) : sin(ang);
  pe[t*DM + c] = (float)vv;
}

// ---------------- 128x128 fp32 GEMM, 256 thr, 8x8/thread, reg prefetch ----------------
__global__ __launch_bounds__(256)
void gemm128(const float* __restrict__ A, const float* __restrict__ B,
             float* __restrict__ C, const float* __restrict__ bias,
             const float* __restrict__ pe, float* __restrict__ mirror,
             int N, int K)
{
  __shared__ float As[16][132];
  __shared__ float Bs[16][132];
  int tid = threadIdx.x;
  int row0 = blockIdx.y << 7, col0 = blockIdx.x << 7;
  int ar = tid >> 1, ak = (tid & 1) << 3;
  int bk = tid >> 4, bn = (tid & 15) << 3;
  int m0 = (tid >> 4) << 3, n0 = (tid & 15) << 3;
  const float* Ap = A + (size_t)(row0 + ar) * K + ak;
  const float* Bp = B + (size_t)bk * N + col0 + bn;
  float4 a0 = *(const float4*)(Ap);
  float4 a1 = *(const float4*)(Ap + 4);
  float4 b0 = *(const float4*)(Bp);
  float4 b1 = *(const float4*)(Bp + 4);
  float acc[8][8] = {};
  for (int k0 = 0; k0 < K; k0 += 16){
    __syncthreads();
    As[ak+0][ar]=a0.x; As[ak+1][ar]=a0.y; As[ak+2][ar]=a0.z; As[ak+3][ar]=a0.w;
    As[ak+4][ar]=a1.x; As[ak+5][ar]=a1.y; As[ak+6][ar]=a1.z; As[ak+7][ar]=a1.w;
    *(float4*)&Bs[bk][bn]   = b0;
    *(float4*)&Bs[bk][bn+4] = b1;
    __syncthreads();
    if (k0 + 16 < K){
      a0 = *(const float4*)(Ap + k0 + 16);
      a1 = *(const float4*)(Ap + k0 + 20);
      b0 = *(const float4*)(Bp + (size_t)(k0+16)*N);
      b1 = *(const float4*)(Bp + (size_t)(k0+16)*N + 4);
    }
    #pragma unroll
    for (int kk = 0; kk < 16; ++kk){
      float4 x0 = *(const float4*)&As[kk][m0];
      float4 x1 = *(const float4*)&As[kk][m0+4];
      float4 y0 = *(const float4*)&Bs[kk][n0];
      float4 y1 = *(const float4*)&Bs[kk][n0+4];
      float xa[8] = {x0.x,x0.y,x0.z,x0.w,x1.x,x1.y,x1.z,x1.w};
      float yb[8] = {y0.x,y0.y,y0.z,y0.w,y1.x,y1.y,y1.z,y1.w};
      #pragma unroll
      for (int i = 0; i < 8; ++i)
        #pragma unroll
        for (int j = 0; j < 8; ++j)
          acc[i][j] += xa[i]*yb[j];
    }
  }
  float badd[8] = {};
  if (bias){
    float4 v0 = *(const float4*)(bias + col0 + n0);
    float4 v1 = *(const float4*)(bias + col0 + n0 + 4);
    badd[0]=v0.x; badd[1]=v0.y; badd[2]=v0.z; badd[3]=v0.w;
    badd[4]=v1.x; badd[5]=v1.y; badd[6]=v1.z; badd[7]=v1.w;
  }
  #pragma unroll
  for (int i = 0; i < 8; ++i){
    int gr = row0 + m0 + i;
    float r[8];
    #pragma unroll
    for (int j = 0; j < 8; ++j) r[j] = acc[i][j] + badd[j];
    if (pe){
      const float* pv = pe + (size_t)(gr % TT)*DM + col0 + n0;
      #pragma unroll
      for (int j = 0; j < 8; ++j) r[j] += pv[j];
    }
    float* cp = C + (size_t)gr*N + col0 + n0;
    *(float4*)cp       = make_float4(r[0],r[1],r[2],r[3]);
    *(float4*)(cp + 4) = make_float4(r[4],r[5],r[6],r[7]);
    if (mirror){
      float* mp = mirror + (size_t)gr*N + col0 + n0;
      *(float4*)mp       = make_float4(r[0],r[1],r[2],r[3]);
      *(float4*)(mp + 4) = make_float4(r[4],r[5],r[6],r[7]);
    }
  }
}

// ---------------- old 64x64 GEMM (kept for the tiny cls matmul, M=32) ----------------
__global__ __launch_bounds__(256)
void gemm_f32(const float* __restrict__ A, const float* __restrict__ Bw,
              float* __restrict__ C, const float* __restrict__ bias,
              float* __restrict__ obf, int M, int N, int K)
{
  __shared__ float As[16][68];
  __shared__ float Bs[16][68];
  int tid = threadIdx.x;
  int row0 = blockIdx.y << 6, col0 = blockIdx.x << 6;
  int ar = tid >> 2, ak = (tid & 3) << 2;
  int bk = tid >> 4, bn = (tid & 15) << 2;
  int n0 = (tid & 15) << 2, m0 = (tid >> 4) << 2;
  float acc[4][4] = {};
  bool arow_ok = (row0 + ar) < M;
  const float* Aldg = A + (size_t)(row0 + ar) * K + ak;
  const float* Bldg = Bw + (size_t)bk * N + col0 + bn;
  for (int k0 = 0; k0 < K; k0 += 16){
    float4 av = make_float4(0.f,0.f,0.f,0.f);
    if (arow_ok) av = *(const float4*)(Aldg + k0);
    float4 bv = *(const float4*)(Bldg + (size_t)k0 * N);
    __syncthreads();
    As[ak+0][ar]=av.x; As[ak+1][ar]=av.y; As[ak+2][ar]=av.z; As[ak+3][ar]=av.w;
    *(float4*)&Bs[bk][bn] = bv;
    __syncthreads();
    #pragma unroll
    for (int kk = 0; kk < 16; ++kk){
      float4 a = *(const float4*)&As[kk][m0];
      float4 b = *(const float4*)&Bs[kk][n0];
      float aa[4] = {a.x,a.y,a.z,a.w};
      float bb[4] = {b.x,b.y,b.z,b.w};
      #pragma unroll
      for (int i = 0; i < 4; ++i)
        #pragma unroll
        for (int j = 0; j < 4; ++j)
          acc[i][j] += aa[i]*bb[j];
    }
  }
  float4 badd = make_float4(0.f,0.f,0.f,0.f);
  if (bias) badd = *(const float4*)(bias + col0 + n0);
  #pragma unroll
  for (int i = 0; i < 4; ++i){
    int gr = row0 + m0 + i;
    if (gr < M){
      float4 r = make_float4(acc[i][0]+badd.x, acc[i][1]+badd.y, acc[i][2]+badd.z, acc[i][3]+badd.w);
      *(float4*)(C + (size_t)gr*N + col0 + n0) = r;
      if (obf) *(float4*)(obf + (size_t)gr*N + col0 + n0) = r;
    }
  }
}

// ---------------- flash-style causal attention (unchanged from R4) ----------------
__global__ __launch_bounds__(256)
void fattn_k(const float* q, const float* __restrict__ k,
             const float* __restrict__ v, float* o)
{
  __shared__ float Qt[64][68];
  __shared__ float KP[64][68];
  __shared__ float Vs[64][68];
  int qt = blockIdx.x, bh = blockIdx.y;
  int b = bh >> 3, h = bh & 7;
  size_t base = (size_t)b * TT * DM + h * 64;
  int tid = threadIdx.x;
  int ty = tid >> 4, tx = tid & 15;
  int m0 = ty << 2, n0 = tx << 2;
  {
    int r = tid >> 2, dd = (tid & 3) << 4;
    int qrow = qt*64 + r;
    const float* qp = q + base + (size_t)(qrow < TT ? qrow : TT-1) * DM;
    #pragma unroll
    for (int u = 0; u < 4; ++u){
      float4 t4 = *(const float4*)(qp + dd + u*4);
      Qt[dd+u*4+0][r]=t4.x; Qt[dd+u*4+1][r]=t4.y; Qt[dd+u*4+2][r]=t4.z; Qt[dd+u*4+3][r]=t4.w;
    }
  }
  float o_acc[4][4] = {};
  float m_i[4], l_i[4];
  #pragma unroll
  for (int i = 0; i < 4; ++i){ m_i[i] = -3e38f; l_i[i] = 0.f; }
  int ktiles = qt + 1;
  for (int kt = 0; kt < ktiles; ++kt){
    __syncthreads();
    {
      int r = tid >> 2, dd = (tid & 3) << 4;
      int jrow = kt*64 + r;
      int jc = jrow < TT ? jrow : TT-1;
      const float* kp = k + base + (size_t)jc * DM;
      const float* vp = v + base + (size_t)jc * DM;
      #pragma unroll
      for (int u = 0; u < 4; ++u){
        float4 t4 = *(const float4*)(kp + dd + u*4);
        KP[dd+u*4+0][r]=t4.x; KP[dd+u*4+1][r]=t4.y; KP[dd+u*4+2][r]=t4.z; KP[dd+u*4+3][r]=t4.w;
        *(float4*)&Vs[r][dd + u*4] = *(const float4*)(vp + dd + u*4);
      }
    }
    __syncthreads();
    float s[4][4] = {};
    #pragma unroll 8
    for (int d = 0; d < 64; ++d){
      float4 a = *(const float4*)&Qt[d][m0];
      float4 bb = *(const float4*)&KP[d][n0];
      float xa[4] = {a.x,a.y,a.z,a.w};
      float yb[4] = {bb.x,bb.y,bb.z,bb.w};
      #pragma unroll
      for (int i = 0; i < 4; ++i)
        #pragma unroll
        for (int j = 0; j < 4; ++j)
          s[i][j] += xa[i]*yb[j];
    }
    int qrow0 = qt*64 + m0, jcol0 = kt*64 + n0;
    #pragma unroll
    for (int i = 0; i < 4; ++i)
      #pragma unroll
      for (int j = 0; j < 4; ++j){
        int jj = jcol0 + j;
        s[i][j] = (jj <= qrow0 + i && jj < TT) ? s[i][j]*0.125f : -3e38f;
      }
    float p[4][4];
    #pragma unroll
    for (int i = 0; i < 4; ++i){
      float mx = fmaxf(fmaxf(s[i][0],s[i][1]), fmaxf(s[i][2],s[i][3]));
      #pragma unroll
      for (int off = 1; off < 16; off <<= 1) mx = fmaxf(mx, __shfl_xor(mx, off, 64));
      float mnew = fmaxf(m_i[i], mx);
      float al = expf(m_i[i] - mnew);
      l_i[i] *= al;
      #pragma unroll
      for (int c = 0; c < 4; ++c) o_acc[i][c] *= al;
      float ps = 0.f;
      #pragma unroll
      for (int j = 0; j < 4; ++j){ p[i][j] = expf(s[i][j] - mnew); ps += p[i][j]; }
      #pragma unroll
      for (int off = 1; off < 16; off <<= 1) ps += __shfl_xor(ps, off, 64);
      l_i[i] += ps;
      m_i[i] = mnew;
    }
    __syncthreads();
    #pragma unroll
    for (int i = 0; i < 4; ++i)
      #pragma unroll
      for (int j = 0; j < 4; ++j)
        KP[n0 + j][m0 + i] = p[i][j];
    __syncthreads();
    #pragma unroll 8
    for (int jj = 0; jj < 64; ++jj){
      float4 a = *(const float4*)&KP[jj][m0];
      float4 bb = *(const float4*)&Vs[jj][n0];
      float xa[4] = {a.x,a.y,a.z,a.w};
      float yb[4] = {bb.x,bb.y,bb.z,bb.w};
      #pragma unroll
      for (int i = 0; i < 4; ++i)
        #pragma unroll
        for (int c = 0; c < 4; ++c)
          o_acc[i][c] += xa[i]*yb[c];
    }
  }
  #pragma unroll
  for (int i = 0; i < 4; ++i){
    int qrow = qt*64 + m0 + i;
    if (qrow < TT){
      float inv = 1.f / l_i[i];
      float4 r = make_float4(o_acc[i][0]*inv, o_acc[i][1]*inv, o_acc[i][2]*inv, o_acc[i][3]*inv);
      *(float4*)(o + base + (size_t)qrow*DM + n0) = r;
    }
  }
}

// ---------------- router: LDS-staged transposed weights, no atomics ----------------
__global__ __launch_bounds__(256)
void router2_k(const float* __restrict__ X, const float* __restrict__ rtW, const float* __restrict__ rtb,
               const float* __restrict__ rnW, const float* __restrict__ rnb, const float* __restrict__ nz,
               int* __restrict__ tok_e, float* __restrict__ tok_g)
{
  __shared__ float Wt[8*513];   // [e][d], stride 513
  __shared__ float Wn[8*513];
  int tid = threadIdx.x;
  for (int i = tid*4; i < DM*8; i += 1024){
    float4 t = *(const float4*)(rtW + i);
    float4 n = *(const float4*)(rnW + i);
    int d = i >> 3, e = i & 7;
    Wt[(e+0)*513 + d] = t.x; Wt[(e+1)*513 + d] = t.y; Wt[(e+2)*513 + d] = t.z; Wt[(e+3)*513 + d] = t.w;
    Wn[(e+0)*513 + d] = n.x; Wn[(e+1)*513 + d] = n.y; Wn[(e+2)*513 + d] = n.z; Wn[(e+3)*513 + d] = n.w;
  }
  __syncthreads();
  int w = tid >> 6, lane = tid & 63;
  int t = (blockIdx.x << 2) + w;
  const float* xr = X + (size_t)t * DM;
  float at[8] = {}, an[8] = {};
  #pragma unroll
  for (int u = 0; u < 8; ++u){
    int d = (u<<6) + lane;
    float xv = xr[d];
    #pragma unroll
    for (int e = 0; e < 8; ++e){
      at[e] += xv * Wt[e*513 + d];
      an[e] += xv * Wn[e*513 + d];
    }
  }
  #pragma unroll
  for (int off = 32; off; off >>= 1){
    #pragma unroll
    for (int e = 0; e < 8; ++e){
      at[e] += __shfl_xor(at[e], off, 64);
      an[e] += __shfl_xor(an[e], off, 64);
    }
  }
  if (lane == 0){
    float ns[8];
    #pragma unroll
    for (int e = 0; e < 8; ++e){
      float lt = at[e] + rtb[e];
      float ln_ = an[e] + rnb[e];
      float sp = (ln_ > 0.f) ? (ln_ + log1pf(expf(-ln_))) : log1pf(expf(ln_));
      ns[e] = lt + nz[(size_t)t*8 + e] * sp;
    }
    int i1 = 0; float n1 = ns[0];
    #pragma unroll
    for (int e = 1; e < 8; ++e) if (ns[e] > n1){ n1 = ns[e]; i1 = e; }
    int i2 = -1; float n2 = -3e38f;
    #pragma unroll
    for (int e = 0; e < 8; ++e) if (e != i1 && ns[e] > n2){ n2 = ns[e]; i2 = e; }
    float ex = expf(n2 - n1);
    float inv = 1.f / (1.f + ex);
    tok_e[t*2]   = i1; tok_g[t*2]   = inv;
    tok_e[t*2+1] = i2; tok_g[t*2+1] = ex * inv;
  }
}

// ---------------- single-block histogram + prefix + slot assignment (LDS atomics) ----------------
__global__ __launch_bounds__(1024)
void route_assign_k(const int* __restrict__ tok_e, int* __restrict__ offs_g,
                    int* __restrict__ idx_c, int* __restrict__ tok_slot)
{
  __shared__ int hist[NE];
  __shared__ int cur[NE];
  int tid = threadIdx.x;
  if (tid < NE) hist[tid] = 0;
  __syncthreads();
  for (int i = tid; i < BT*2; i += 1024) atomicAdd(&hist[tok_e[i]], 1);
  __syncthreads();
  if (tid == 0){
    int s = 0;
    for (int e = 0; e < NE; ++e){ offs_g[e] = s; cur[e] = s; s += hist[e]; }
    offs_g[NE] = s;
  }
  __syncthreads();
  for (int i = tid; i < BT*2; i += 1024){
    int e = tok_e[i];
    int p = atomicAdd(&cur[e], 1);
    idx_c[p] = i >> 1;
    tok_slot[i] = p;
  }
}

// ---------------- MoE GEMM1 (128x128, gathered rows), chunk width fcw ----------------
__global__ __launch_bounds__(256)
void moe1_128(const float* __restrict__ X, const float* __restrict__ Wi,
              const float* __restrict__ bi, const int* __restrict__ offs,
              const int* __restrict__ idx_c, float* __restrict__ H1, int c0, int fcw)
{
  int e = blockIdx.z;
  int base = offs[e], cnt = offs[e+1] - base;
  int row0 = blockIdx.y << 7;
  if (row0 >= cnt) return;
  int col0 = blockIdx.x << 7;
  __shared__ float As[16][132];
  __shared__ float Bs[16][132];
  int tid = threadIdx.x;
  int ar = tid >> 1, ak = (tid & 1) << 3;
  int bk = tid >> 4, bn = (tid & 15) << 3;
  int m0 = (tid >> 4) << 3, n0 = (tid & 15) << 3;
  int rr = (row0 + ar < cnt) ? idx_c[base + row0 + ar] : -1;
  const float* Ap = (rr >= 0) ? (X + (size_t)rr*DM + ak) : nullptr;
  const float* Bp = Wi + (size_t)e * DM * FFD + c0 + (size_t)bk * FFD + col0 + bn;
  float4 zero = make_float4(0.f,0.f,0.f,0.f);
  float4 a0 = Ap ? *(const float4*)(Ap)     : zero;
  float4 a1 = Ap ? *(const float4*)(Ap + 4) : zero;
  float4 b0 = *(const float4*)(Bp);
  float4 b1 = *(const float4*)(Bp + 4);
  float acc[8][8] = {};
  for (int k0 = 0; k0 < DM; k0 += 16){
    __syncthreads();
    As[ak+0][ar]=a0.x; As[ak+1][ar]=a0.y; As[ak+2][ar]=a0.z; As[ak+3][ar]=a0.w;
    As[ak+4][ar]=a1.x; As[ak+5][ar]=a1.y; As[ak+6][ar]=a1.z; As[ak+7][ar]=a1.w;
    *(float4*)&Bs[bk][bn]   = b0;
    *(float4*)&Bs[bk][bn+4] = b1;
    __syncthreads();
    if (k0 + 16 < DM){
      if (Ap){ a0 = *(const float4*)(Ap + k0 + 16); a1 = *(const float4*)(Ap + k0 + 20); }
      b0 = *(const float4*)(Bp + (size_t)(k0+16)*FFD);
      b1 = *(const float4*)(Bp + (size_t)(k0+16)*FFD + 4);
    }
    #pragma unroll
    for (int kk = 0; kk < 16; ++kk){
      float4 x0 = *(const float4*)&As[kk][m0];
      float4 x1 = *(const float4*)&As[kk][m0+4];
      float4 y0 = *(const float4*)&Bs[kk][n0];
      float4 y1 = *(const float4*)&Bs[kk][n0+4];
      float xa[8] = {x0.x,x0.y,x0.z,x0.w,x1.x,x1.y,x1.z,x1.w};
      float yb[8] = {y0.x,y0.y,y0.z,y0.w,y1.x,y1.y,y1.z,y1.w};
      #pragma unroll
      for (int i = 0; i < 8; ++i)
        #pragma unroll
        for (int j = 0; j < 8; ++j)
          acc[i][j] += xa[i]*yb[j];
    }
  }
  float bb8[8];
  {
    const float* bp = bi + (size_t)e*FFD + c0 + col0 + n0;
    #pragma unroll
    for (int j = 0; j < 8; ++j) bb8[j] = bp[j];
  }
  #pragma unroll
  for (int i = 0; i < 8; ++i){
    int r = row0 + m0 + i;
    if (r < cnt){
      float* hp = H1 + (size_t)(base + r)*fcw + col0 + n0;
      *(float4*)hp     = make_float4(fmaxf(acc[i][0]+bb8[0],0.f), fmaxf(acc[i][1]+bb8[1],0.f),
                                     fmaxf(acc[i][2]+bb8[2],0.f), fmaxf(acc[i][3]+bb8[3],0.f));
      *(float4*)(hp+4) = make_float4(fmaxf(acc[i][4]+bb8[4],0.f), fmaxf(acc[i][5]+bb8[5],0.f),
                                     fmaxf(acc[i][6]+bb8[6],0.f), fmaxf(acc[i][7]+bb8[7],0.f));
    }
  }
}

// ---------------- MoE GEMM2 (128x128, slot-space, no atomics), K = fcw per pass ----------------
__global__ __launch_bounds__(256)
void moe2_128(const float* __restrict__ H1, const float* __restrict__ Wo,
              const float* __restrict__ bo, const int* __restrict__ offs,
              float* __restrict__ Ye, int c0, int fcw)
{
  int e = blockIdx.z;
  int base = offs[e], cnt = offs[e+1] - base;
  int row0 = blockIdx.y << 7;
  if (row0 >= cnt) return;
  int col0 = blockIdx.x << 7;
  __shared__ float As[16][132];
  __shared__ float Bs[16][132];
  int tid = threadIdx.x;
  int ar = tid >> 1, ak = (tid & 1) << 3;
  int bk = tid >> 4, bn = (tid & 15) << 3;
  int m0 = (tid >> 4) << 3, n0 = (tid & 15) << 3;
  bool arow_ok = (row0 + ar) < cnt;
  const float* Ap = H1 + (size_t)(base + row0 + ar)*fcw + ak;
  const float* Bp = Wo + (size_t)e * FFD * DM + (size_t)(c0 + bk) * DM + col0 + bn;
  float4 zero = make_float4(0.f,0.f,0.f,0.f);
  float4 a0 = arow_ok ? *(const float4*)(Ap)     : zero;
  float4 a1 = arow_ok ? *(const float4*)(Ap + 4) : zero;
  float4 b0 = *(const float4*)(Bp);
  float4 b1 = *(const float4*)(Bp + 4);
  float acc[8][8] = {};
  for (int k0 = 0; k0 < fcw; k0 += 16){
    __syncthreads();
    As[ak+0][ar]=a0.x; As[ak+1][ar]=a0.y; As[ak+2][ar]=a0.z; As[ak+3][ar]=a0.w;
    As[ak+4][ar]=a1.x; As[ak+5][ar]=a1.y; As[ak+6][ar]=a1.z; As[ak+7][ar]=a1.w;
    *(float4*)&Bs[bk][bn]   = b0;
    *(float4*)&Bs[bk][bn+4] = b1;
    __syncthreads();
    if (k0 + 16 < fcw){
      if (arow_ok){ a0 = *(const float4*)(Ap + k0 + 16); a1 = *(const float4*)(Ap + k0 + 20); }
      b0 = *(const float4*)(Bp + (size_t)(k0+16)*DM);
      b1 = *(const float4*)(Bp + (size_t)(k0+16)*DM + 4);
    }
    #pragma unroll
    for (int kk = 0; kk < 16; ++kk){
      float4 x0 = *(const float4*)&As[kk][m0];
      float4 x1 = *(const float4*)&As[kk][m0+4];
      float4 y0 = *(const float4*)&Bs[kk][n0];
      float4 y1 = *(const float4*)&Bs[kk][n0+4];
      float xa[8] = {x0.x,x0.y,x0.z,x0.w,x1.x,x1.y,x1.z,x1.w};
      float yb[8] = {y0.x,y0.y,y0.z,y0.w,y1.x,y1.y,y1.z,y1.w};
      #pragma unroll
      for (int i = 0; i < 8; ++i)
        #pragma unroll
        for (int j = 0; j < 8; ++j)
          acc[i][j] += xa[i]*yb[j];
    }
  }
  #pragma unroll
  for (int i = 0; i < 8; ++i){
    int r = row0 + m0 + i;
    if (r < cnt){
      float* yp = Ye + (size_t)(base + r)*DM + col0 + n0;
      if (c0 == 0){
        const float* bp = bo + (size_t)e*DM + col0 + n0;
        *(float4*)yp     = make_float4(acc[i][0]+bp[0], acc[i][1]+bp[1], acc[i][2]+bp[2], acc[i][3]+bp[3]);
        *(float4*)(yp+4) = make_float4(acc[i][4]+bp[4], acc[i][5]+bp[5], acc[i][6]+bp[6], acc[i][7]+bp[7]);
      } else {
        float4 o0 = *(const float4*)yp;
        float4 o1 = *(const float4*)(yp+4);
        *(float4*)yp     = make_float4(o0.x+acc[i][0], o0.y+acc[i][1], o0.z+acc[i][2], o0.w+acc[i][3]);
        *(float4*)(yp+4) = make_float4(o1.x+acc[i][4], o1.y+acc[i][5], o1.z+acc[i][6], o1.w+acc[i][7]);
      }
    }
  }
}

// ---------------- gated combine + layernorm ----------------
__global__ __launch_bounds__(256)
void combine_ln_k(const float* __restrict__ Ye, const int* __restrict__ tok_slot,
                  const float* __restrict__ tok_g, const float* __restrict__ g,
                  const float* __restrict__ bb, float* __restrict__ F)
{
  int t = blockIdx.x, tid = threadIdx.x;
  int s1 = tok_slot[t*2], s2 = tok_slot[t*2+1];
  float g1 = tok_g[t*2], g2 = tok_g[t*2+1];
  const float* y1 = Ye + (size_t)s1*DM;
  const float* y2 = Ye + (size_t)s2*DM;
  float v0 = g1*y1[tid]     + g2*y2[tid];
  float v1 = g1*y1[tid+256] + g2*y2[tid+256];
  __shared__ float red[8];
  int w = tid >> 6, lane = tid & 63;
  float s = v0 + v1;
  #pragma unroll
  for (int off = 32; off; off >>= 1) s += __shfl_xor(s, off, 64);
  if (lane == 0) red[w] = s;
  __syncthreads();
  float mu = (red[0]+red[1]+red[2]+red[3]) * (1.f/512.f);
  float d0 = v0 - mu, d1 = v1 - mu;
  float q2 = d0*d0 + d1*d1;
  #pragma unroll
  for (int off = 32; off; off >>= 1) q2 += __shfl_xor(q2, off, 64);
  if (lane == 0) red[4+w] = q2;
  __syncthreads();
  float var = (red[4]+red[5]+red[6]+red[7]) * (1.f/512.f);
  float r = 1.f / sqrtf(var + 1e-5f);
  F[(size_t)t*DM + tid]       = d0*r*g[tid]     + bb[tid];
  F[(size_t)t*DM + tid + 256] = d1*r*g[tid+256] + bb[tid+256];
}

// ---------------- global = sum over T of second_vector ----------------
__global__ void gsum_k(const float* __restrict__ sv, float* __restrict__ gb, float* __restrict__ gout){
  int i = blockIdx.x*256 + threadIdx.x;
  int b = i >> 9, d = i & 511;
  const float* p = sv + (size_t)b*TT*DM + d;
  float s = 0.f;
  for (int t = 0; t < TT; ++t) s += p[(size_t)t*DM];
  gb[i] = s; gout[i] = s;
}

extern "C" void kernel_launch(void* const* d_in, const int* in_sizes, int n_in,
                              void* d_out, int out_size, void* d_ws, size_t ws_size,
                              hipStream_t stream)
{
  (void)in_sizes; (void)n_in; (void)out_size;
  const float* xin   = (const float*)d_in[0];
  const float* pembW = (const float*)d_in[1];
  const float* pembB = (const float*)d_in[2];
  const float* vecW  = (const float*)d_in[3];
  const float* vecB  = (const float*)d_in[4];
  const float* clsW  = (const float*)d_in[5];
  const float* clsB  = (const float*)d_in[6];
  float* out = (float*)d_out;

  // ---- choose MoE chunk width by available workspace (deterministic per run) ----
  const size_t SMALL = 16384*2 + 12544*5 + 32;   // gbv, clsbuf, tok_g, tok_e, tok_slot, idx_c, offs...
  int fcw = 256;
  for (int cand = 2048; cand >= 256; cand >>= 1){
    size_t need = ((size_t)4*ABUF + (size_t)12544*cand + SMALL) * sizeof(float);
    if (need <= ws_size){ fcw = cand; break; }
  }
  size_t h1e = (size_t)12544 * fcw;

  float* ws = (float*)d_ws;
  float* A0   = ws;
  float* A1   = A0 + ABUF;
  float* A2   = A1 + ABUF;           // Yexp spans A2..A3 (12544*512)
  float* A3   = A2 + ABUF;
  float* H1   = A3 + ABUF;           // 12544*fcw
  float* Yexp = A2;
  float* patches = H1;               // aliases, dead before MoE
  float* pe      = H1 + 1605632;
  float* gbv    = H1 + h1e;
  float* clsbuf = gbv + 16384;
  float* tok_g  = clsbuf + 16384;
  int*   tok_e  = (int*)(tok_g + 12544);
  int*   tok_slot = tok_e + 12544;
  int*   idx_c  = tok_slot + 12544;
  int*   offs   = idx_c + 12544;     // 9 ints

  patchify_k<<<dim3(BT), dim3(256), 0, stream>>>(xin, patches);
  posenc_k<<<dim3(TT), dim3(512), 0, stream>>>(pe);
  gemm128<<<dim3(4,49), dim3(256), 0, stream>>>(patches, pembW, A1, pembB, pe, nullptr, DM, 256);

  float* P = A1;
  float* Q = A0;
  for (int l = 0; l < 2; ++l){
    int base = 7 + 18*l;
    const float* pW  = (const float*)d_in[base+0];
    const float* pb  = (const float*)d_in[base+1];
    const float* Wq  = (const float*)d_in[base+2];
    const float* Wk  = (const float*)d_in[base+3];
    const float* Wv  = (const float*)d_in[base+4];
    const float* Wo  = (const float*)d_in[base+5];
    const float* bo  = (const float*)d_in[base+6];
    const float* rtW = (const float*)d_in[base+7];
    const float* rtb = (const float*)d_in[base+8];
    const float* rnW = (const float*)d_in[base+9];
    const float* rnb = (const float*)d_in[base+10];
    const float* eWi = (const float*)d_in[base+11];
    const float* ebi = (const float*)d_in[base+12];
    const float* eWo = (const float*)d_in[base+13];
    const float* ebo = (const float*)d_in[base+14];
    const float* lng = (const float*)d_in[base+15];
    const float* lnb = (const float*)d_in[base+16];
    const float* nz  = (const float*)d_in[base+17];

    gemm128<<<dim3(4,49), dim3(256), 0, stream>>>(P, pW, Q, pb, nullptr, nullptr, DM, DM);
    gemm128<<<dim3(4,49), dim3(256), 0, stream>>>(Q, Wq, P, nullptr, nullptr, nullptr, DM, DM);
    gemm128<<<dim3(4,49), dim3(256), 0, stream>>>(Q, Wk, A2, nullptr, nullptr, nullptr, DM, DM);
    gemm128<<<dim3(4,49), dim3(256), 0, stream>>>(Q, Wv, A3, nullptr, nullptr, nullptr, DM, DM);
    fattn_k<<<dim3(4,256), dim3(256), 0, stream>>>(P, A2, A3, P);
    gemm128<<<dim3(4,49), dim3(256), 0, stream>>>(P, Wo, Q, bo, nullptr, nullptr, DM, DM);
    // routing
    router2_k<<<dim3(BT/4), dim3(256), 0, stream>>>(Q, rtW, rtb, rnW, rnb, nz, tok_e, tok_g);
    route_assign_k<<<dim3(1), dim3(1024), 0, stream>>>(tok_e, offs, idx_c, tok_slot);
    // experts (chunked only if workspace forces it)
    for (int c0 = 0; c0 < FFD; c0 += fcw){
      moe1_128<<<dim3(fcw/128, 49, NE), dim3(256), 0, stream>>>(Q, eWi, ebi, offs, idx_c, H1, c0, fcw);
      moe2_128<<<dim3(DM/128, 49, NE), dim3(256), 0, stream>>>(H1, eWo, ebo, offs, Yexp, c0, fcw);
    }
    combine_ln_k<<<dim3(BT), dim3(256), 0, stream>>>(Yexp, tok_slot, tok_g, lng, lnb, P);
    float* mirror = out + (size_t)l * ABUF;
    gemm128<<<dim3(4,49), dim3(256), 0, stream>>>(P, vecW, Q, vecB, nullptr, mirror, DM, DM);
    float* tmp = P; P = Q; Q = tmp;
  }

  gsum_k<<<dim3(64), dim3(256), 0, stream>>>(P, gbv, out + 2*ABUF);
  gemm_f32<<<dim3(8,1), dim3(256), 0, stream>>>(gbv, clsW, clsbuf, clsB, out + 2*ABUF + 16384, 32, DM, DM);
}